// Round 16
// baseline (226.897 us; speedup 1.0000x reference)
//
#include <hip/hip_runtime.h>

// ---------------------------------------------------------------------------
// Soft decision tree forward (all-f16), round 16: r14 mega-kernel + split-K
// phase-A overlap (X half-1 HBM load hidden under K-steps 0..15).
//   d = sigmoid(X @ T^T); leaf probs = depth-10 path products;
//   out = softmax(probs @ L)
//
// Identical to round 14 except phase A: X is staged per K-half (64KB each);
// half 0 synchronously, half 1 loaded in two register batches and ds_written
// between K-step pairs (dbuf region, no WAR), one lgkm+barrier before step 16.
// LDS layout, K-loop bodies, expansion, probs write, gemm2, softmax: frozen.
// Canary: absmax must read exactly 0.0004882812.
// ---------------------------------------------------------------------------

typedef unsigned short u16;
typedef unsigned short u16x8 __attribute__((ext_vector_type(8)));
typedef _Float16 f16;
typedef _Float16 f16x8 __attribute__((ext_vector_type(8)));
typedef float f32x4 __attribute__((ext_vector_type(4)));

#define BATCH 32768
#define DIM   1024
#define NPAD  1024
#define DSTRIDE 2112

#define BARRIER()  asm volatile("s_barrier" ::: "memory")

// ---- f16 helpers ----
__device__ __forceinline__ u16 f2h(float f) {
    union { f16 h; u16 u; } v; v.h = (f16)f; return v.u;
}
__device__ __forceinline__ float h2f(u16 u) {
    union { u16 u; f16 h; } v; v.u = u; return (float)v.h;
}

#define MFMA16(a, b, c) __builtin_amdgcn_mfma_f32_16x16x32_f16(a, b, c, 0, 0, 0)

// ---------------------------------------------------------------------------
// prep: thresholds -> Bpk1 fragment-packed f16 (node row 1023 = 0; frozen)
// ---------------------------------------------------------------------------
__global__ __launch_bounds__(256) void prep_tp(const float* __restrict__ t,
                                               u16* __restrict__ Bpk1) {
    int o = (blockIdx.x * 256 + threadIdx.x) * 4;
    int n16  = o >> 14;
    int kt   = (o >> 9) & 31;
    int lane = (o >> 3) & 63;
    int j0   = o & 7;
    int mr = lane & 15, kg = lane >> 4;
    int node = n16 * 16 + mr;
    int k0  = kt * 32 + kg * 8 + j0;
    ushort4 v = make_ushort4(0, 0, 0, 0);
    if (node < 1023) {
        const float* src = t + (size_t)node * 1024 + k0;
        v.x = f2h(src[0]); v.y = f2h(src[1]);
        v.z = f2h(src[2]); v.w = f2h(src[3]);
    }
    *(ushort4*)&Bpk1[o] = v;
}

// ---------------------------------------------------------------------------
// prep: L -> BpkL fragment-packed f16 (frozen)
// ---------------------------------------------------------------------------
__global__ __launch_bounds__(256) void prep_lt(const float* __restrict__ L,
                                               u16* __restrict__ BpkL) {
    int o = (blockIdx.x * 256 + threadIdx.x) * 4;
    int b16  = o >> 14;
    int kt   = (o >> 9) & 31;
    int lane = (o >> 3) & 63;
    int j0   = o & 7;
    int mr = lane & 15, kg = lane >> 4;
    int col = b16 * 16 + mr;
    int k0  = kt * 32 + kg * 8 + j0;
    ushort4 v;
    v.x = f2h(L[(size_t)(k0 + 0) * 1024 + col]);
    v.y = f2h(L[(size_t)(k0 + 1) * 1024 + col]);
    v.z = f2h(L[(size_t)(k0 + 2) * 1024 + col]);
    v.w = f2h(L[(size_t)(k0 + 3) * 1024 + col]);
    *(ushort4*)&BpkL[o] = v;
}

// ---------------------------------------------------------------------------
// MEGA KERNEL (64 rows / block, 16 waves; r14 structure + split-K phase A)
// ---------------------------------------------------------------------------
__global__ __launch_bounds__(1024, 1) void megak(
    const float* __restrict__ X, const u16* __restrict__ Bpk1,
    const u16* __restrict__ BpkL, float* __restrict__ out)
{
    __shared__ __align__(16) char lds[135168];
    const int t = threadIdx.x, wid = t >> 6, lane = t & 63;
    const int mr = lane & 15, kg = lane >> 4;
    const int rb = blockIdx.x * 64;
    const int fq = kg * 4;

    const u16* bbase1[4];
#pragma unroll
    for (int n = 0; n < 4; ++n)
        bbase1[n] = Bpk1 + (size_t)(wid * 4 + n) * 16384 + (unsigned)lane * 8u;

    f16x8 bA[4], bB[4];

    // ---------------- phase A (split-K): X f32 -> f16 LDS [64][2048B] ------
    // Layout identical to r14: row byte w holds global f16-k-byte
    // (w ^ ((row&7)<<4)). Per half h (k-bytes [h*1024, h*1024+1024)):
    // chunk c in [0,4): row = c*16 + wid; lane covers bytes lane*16.
    const unsigned axoff = (unsigned)(lane * 16);
    auto aload = [&](int h, int c, float4& lo, float4& hi) {
        int row = c * 16 + wid;
        unsigned key = (unsigned)(row & 7) << 4;
        const float* src = X + (size_t)(rb + row) * 1024 + h * 512 + ((axoff ^ key) >> 1);
        lo = *(const float4*)src;
        hi = *(const float4*)(src + 4);
    };
    auto awrite = [&](int h, int c, float4 lo, float4 hi) {
        int row = c * 16 + wid;
        u16x8 v;
        v[0] = f2h(lo.x); v[1] = f2h(lo.y); v[2] = f2h(lo.z); v[3] = f2h(lo.w);
        v[4] = f2h(hi.x); v[5] = f2h(hi.y); v[6] = f2h(hi.z); v[7] = f2h(hi.w);
        *(u16x8*)(lds + row * 2048 + h * 1024 + lane * 16) = v;
    };

    {
        float4 l0[4], h0[4];
#pragma unroll
        for (int c = 0; c < 4; ++c) aload(0, c, l0[c], h0[c]);
        // b1(0) issued after half-0 X loads (youngest) -> stays in flight
#pragma unroll
        for (int n = 0; n < 4; ++n) bA[n] = *(const f16x8*)(bbase1[n]);
#pragma unroll
        for (int c = 0; c < 4; ++c) awrite(0, c, l0[c], h0[c]);
    }
    asm volatile("s_waitcnt lgkmcnt(0)" ::: "memory");
    BARRIER();   // half 0 visible to all waves

    // ---------------- phase B: gemm1 barrier-free K-loop (split) ----------
    const unsigned keyA1 = (unsigned)(mr & 7) << 4;
    unsigned offA1[4];
#pragma unroll
    for (int m = 0; m < 4; ++m) offA1[m] = (unsigned)((m * 16 + mr) * 2048);

    f32x4 acc[4][4];
#pragma unroll
    for (int m = 0; m < 4; ++m)
#pragma unroll
        for (int n = 0; n < 4; ++n) acc[m][n] = (f32x4){0.f, 0.f, 0.f, 0.f};

    auto step1 = [&](int kt, f16x8 (&bu)[4], f16x8 (&bl)[4]) {
        if (kt + 1 < 32) {
#pragma unroll
            for (int n = 0; n < 4; ++n)
                bl[n] = *(const f16x8*)(bbase1[n] + (unsigned)(kt + 1) * 512u);
        }
        const unsigned ko = ((unsigned)(kt * 64) + (unsigned)kg * 16u) ^ keyA1;
        f16x8 a[4];
#pragma unroll
        for (int m = 0; m < 4; ++m)
            a[m] = *(const f16x8*)(lds + offA1[m] + ko);
        __builtin_amdgcn_s_setprio(1);
#pragma unroll
        for (int m = 0; m < 4; ++m)
#pragma unroll
            for (int n = 0; n < 4; ++n)
                acc[m][n] = MFMA16(a[m], bu[n], acc[m][n]);
        __builtin_amdgcn_s_setprio(0);
    };

    {
        float4 xl[2], xh[2];
        // batch a of half 1 (chunks 0,1) issued before steps 0..5
        aload(1, 0, xl[0], xh[0]);
        aload(1, 1, xl[1], xh[1]);
#pragma unroll 1
        for (int k2 = 0; k2 < 3; ++k2) {
            step1(2 * k2, bA, bB);
            step1(2 * k2 + 1, bB, bA);
        }
        awrite(1, 0, xl[0], xh[0]);
        awrite(1, 1, xl[1], xh[1]);
        // batch b of half 1 (chunks 2,3) before steps 6..11
        aload(1, 2, xl[0], xh[0]);
        aload(1, 3, xl[1], xh[1]);
#pragma unroll 1
        for (int k2 = 3; k2 < 6; ++k2) {
            step1(2 * k2, bA, bB);
            step1(2 * k2 + 1, bB, bA);
        }
        awrite(1, 2, xl[0], xh[0]);
        awrite(1, 3, xl[1], xh[1]);
        // steps 12..15
#pragma unroll 1
        for (int k2 = 6; k2 < 8; ++k2) {
            step1(2 * k2, bA, bB);
            step1(2 * k2 + 1, bB, bA);
        }
    }
    asm volatile("s_waitcnt lgkmcnt(0)" ::: "memory");
    BARRIER();   // half 1 visible to all waves
#pragma unroll 1
    for (int k2 = 8; k2 < 16; ++k2) {
        step1(2 * k2, bA, bB);
        step1(2 * k2 + 1, bB, bA);
    }

    // ---------------- phase C: sigmoid -> d into LDS [64][2112B] ----------
    __syncthreads();     // all waves done reading Xh-LDS
#pragma unroll
    for (int m = 0; m < 4; ++m)
#pragma unroll
        for (int j = 0; j < 4; ++j) {
            int row = m * 16 + fq + j;
            unsigned wkey = ((unsigned)((row >> 2) & 3)) << 4;
            char* drow = lds + row * DSTRIDE;
#pragma unroll
            for (int n = 0; n < 4; ++n) {
                int col = wid * 64 + n * 16 + mr;
                float s = acc[m][n][j];
                float dv = 1.0f / (1.0f + __expf(-s));
                *(u16*)(drow + ((2u + 2u * (unsigned)col) ^ wkey)) = f2h(dv);
            }
        }
    __syncthreads();     // d complete

    // ---------------- phase D: tree expansion (frozen) --------------------
    u16x8 pk[4][2];
#pragma unroll
    for (int r = 0; r < 4; ++r) {
        const int lrow = wid * 4 + r;
        const char* dro = lds + lrow * DSTRIDE;
        const unsigned dkey = ((unsigned)((lrow >> 2) & 3)) << 4;
        const int l = lane;

        float prod = 1.0f;
#pragma unroll
        for (int lev = 0; lev < 6; lev++) {
            int node = (1 << lev) - 1 + (l >> (6 - lev));
            int bit  = (l >> (5 - lev)) & 1;
            float v = h2f(*(const u16*)(dro + ((2u + 2u * (unsigned)node) ^ dkey)));
            prod *= bit ? (1.0f - v) : v;
        }
        float d6 = h2f(*(const u16*)(dro + ((2u + 2u * (unsigned)(63 + l)) ^ dkey)));
        ushort2 p7 = *(const ushort2*)(dro + ((256u + 4u * (unsigned)l) ^ dkey));
        ushort4 p8 = *(const ushort4*)(dro + ((512u + 8u * (unsigned)l) ^ dkey));
        u16x8   p9 = *(const u16x8*)(dro + ((1024u + 16u * (unsigned)l) ^ dkey));
        float d7[2] = {h2f(p7.x), h2f(p7.y)};
        float d8[4] = {h2f(p8.x), h2f(p8.y), h2f(p8.z), h2f(p8.w)};
        float d9[8];
#pragma unroll
        for (int j = 0; j < 8; j++) d9[j] = h2f(p9[j]);

        u16 outv[16];
#pragma unroll
        for (int j = 0; j < 16; j++) {
            float f6 = (j >> 3) ? (1.0f - d6) : d6;
            float v7 = d7[j >> 3];  float f7 = ((j >> 2) & 1) ? (1.0f - v7) : v7;
            float v8 = d8[j >> 2];  float f8 = ((j >> 1) & 1) ? (1.0f - v8) : v8;
            float v9 = d9[j >> 1];  float f9 = (j & 1) ? (1.0f - v9) : v9;
            outv[j] = f2h(prod * f6 * f7 * f8 * f9);
        }
        pk[r][0] = (u16x8){outv[0], outv[1], outv[2], outv[3],
                           outv[4], outv[5], outv[6], outv[7]};
        pk[r][1] = (u16x8){outv[8], outv[9], outv[10], outv[11],
                           outv[12], outv[13], outv[14], outv[15]};
    }
    __syncthreads();     // all d reads done before probs overwrite

    // packed probs write, slot-XOR (kt&7) (frozen)
    {
        const int ktw = lane >> 1, kg0 = (lane & 1) * 2;
        const unsigned K = (unsigned)(ktw & 7);
#pragma unroll
        for (int r = 0; r < 4; ++r) {
            const int lrow = wid * 4 + r;
            const int m = lrow >> 4, mrr = lrow & 15;
            char* base = lds + (((ktw << 2) + m) << 10);
            unsigned s0 = ((unsigned)(kg0 * 16 + mrr)) ^ K;
            unsigned s1 = ((unsigned)((kg0 + 1) * 16 + mrr)) ^ K;
            *(u16x8*)(base + s0 * 16) = pk[r][0];
            *(u16x8*)(base + s1 * 16) = pk[r][1];
        }
    }
    __syncthreads();     // probs complete

    // ---------------- phase E: gemm2 barrier-free K-loop (frozen) ---------
    const u16* bbase2 = BpkL + (size_t)(wid * 4) * 16384 + (unsigned)lane * 8u;

#pragma unroll
    for (int m = 0; m < 4; ++m)
#pragma unroll
        for (int n = 0; n < 4; ++n) acc[m][n] = (f32x4){0.f, 0.f, 0.f, 0.f};

#pragma unroll
    for (int n = 0; n < 4; ++n) bA[n] = *(const f16x8*)(bbase2 + n * 16384);

    auto step2 = [&](int kt, f16x8 (&bu)[4], f16x8 (&bl)[4]) {
        if (kt + 1 < 32) {
#pragma unroll
            for (int n = 0; n < 4; ++n)
                bl[n] = *(const f16x8*)(bbase2 + n * 16384 + (unsigned)(kt + 1) * 512u);
        }
        const unsigned sl = ((unsigned)(lane ^ (kt & 7))) << 4;
        f16x8 a[4];
#pragma unroll
        for (int m = 0; m < 4; ++m)
            a[m] = *(const f16x8*)(lds + (((kt << 2) + m) << 10) + sl);
        __builtin_amdgcn_s_setprio(1);
#pragma unroll
        for (int m = 0; m < 4; ++m)
#pragma unroll
            for (int n = 0; n < 4; ++n)
                acc[m][n] = MFMA16(a[m], bu[n], acc[m][n]);
        __builtin_amdgcn_s_setprio(0);
    };

#pragma unroll 1
    for (int k2 = 0; k2 < 16; ++k2) {
        step2(2 * k2, bA, bB);
        step2(2 * k2 + 1, bB, bA);
    }

    __syncthreads();     // all probs reads done before red reuse

    // ---------------- phase F: in-register softmax (frozen) ---------------
    float* red  = (float*)lds;            // [64][16] max
    float* red2 = (float*)(lds + 4096);   // [64][16] sum

    float mx[4][4];
#pragma unroll
    for (int m = 0; m < 4; ++m)
#pragma unroll
        for (int j = 0; j < 4; ++j) {
            float v = acc[m][0][j];
#pragma unroll
            for (int n = 1; n < 4; ++n) v = fmaxf(v, acc[m][n][j]);
#pragma unroll
            for (int off = 1; off < 16; off <<= 1)
                v = fmaxf(v, __shfl_xor(v, off));
            mx[m][j] = v;
        }
    if (mr == 0) {
#pragma unroll
        for (int m = 0; m < 4; ++m)
#pragma unroll
            for (int j = 0; j < 4; ++j)
                red[(m * 16 + fq + j) * 16 + wid] = mx[m][j];
    }
    __syncthreads();
    if (t < 64) {
        float v = red[t * 16];
#pragma unroll
        for (int w = 1; w < 16; ++w) v = fmaxf(v, red[t * 16 + w]);
        red[t * 16] = v;
    }
    __syncthreads();

    float sm[4][4];
#pragma unroll
    for (int m = 0; m < 4; ++m)
#pragma unroll
        for (int j = 0; j < 4; ++j) {
            float M = red[(m * 16 + fq + j) * 16];
            float s = 0.f;
#pragma unroll
            for (int n = 0; n < 4; ++n) {
                float e = __expf(acc[m][n][j] - M);
                acc[m][n][j] = e;
                s += e;
            }
#pragma unroll
            for (int off = 1; off < 16; off <<= 1)
                s += __shfl_xor(s, off);
            sm[m][j] = s;
        }
    if (mr == 0) {
#pragma unroll
        for (int m = 0; m < 4; ++m)
#pragma unroll
            for (int j = 0; j < 4; ++j)
                red2[(m * 16 + fq + j) * 16 + wid] = sm[m][j];
    }
    __syncthreads();
    if (t < 64) {
        float v = 0.f;
#pragma unroll
        for (int w = 0; w < 16; ++w) v += red2[t * 16 + w];
        red2[t * 16] = 1.0f / v;
    }
    __syncthreads();

#pragma unroll
    for (int m = 0; m < 4; ++m)
#pragma unroll
        for (int j = 0; j < 4; ++j) {
            int grow = rb + m * 16 + fq + j;
            float inv = red2[(m * 16 + fq + j) * 16];
#pragma unroll
            for (int n = 0; n < 4; ++n) {
                int gcol = wid * 64 + n * 16 + mr;
                out[(size_t)grow * 1024 + gcol] = acc[m][n][j] * inv;
            }
        }
}

// ---------------------------------------------------------------------------
extern "C" void kernel_launch(void* const* d_in, const int* in_sizes, int n_in,
                              void* d_out, int out_size, void* d_ws, size_t ws_size,
                              hipStream_t stream) {
    const float* x  = (const float*)d_in[0];
    const float* ft = (const float*)d_in[1];
    const float* lp = (const float*)d_in[2];
    float* out = (float*)d_out;
    char* ws = (char*)d_ws;

    // ws layout: Bpk1 2Mi | BpkL 2Mi
    u16* Bpk1 = (u16*)ws;
    u16* BpkL = Bpk1 + (size_t)NPAD * DIM;

    prep_tp<<<1024, 256, 0, stream>>>(ft, Bpk1);
    prep_lt<<<1024, 256, 0, stream>>>(lp, BpkL);
    megak<<<512, 1024, 0, stream>>>(x, Bpk1, BpkL, out);
}

// Round 17
// 185.416 us; speedup vs baseline: 1.2237x; 1.2237x over previous
//
#include <hip/hip_runtime.h>

// ---------------------------------------------------------------------------
// Soft decision tree forward (all-f16), round 17 = round 14 exact revert
// (best measured: 184.0 us total; r15 smaller-blocks and r16 split-K-overlap
// both regressed — r16 via register spills to scratch, +100MB WRITE).
//   d = sigmoid(X @ T^T); leaf probs = depth-10 path products;
//   out = softmax(probs @ L)
//
// Mega-kernel: 64-row blocks, 1024 thr / 16 waves; phases:
//   A) X f32 -> f16 LDS [64][2048B] (coalesced float4 pairs, XOR-swizzled);
//   B) gemm1 barrier-free K-loop (A ds_read, B=Bpk1 packed direct-reg dbuf);
//   C) sigmoid -> d LDS [64][2112B];  D) tree expansion -> packed probs LDS
//      (slot-XOR);  E) gemm2 barrier-free K-loop (B=BpkL direct-reg);
//   F) in-register softmax -> f32 out.
// Canary: absmax exactly 0.0004882812.
// ---------------------------------------------------------------------------

typedef unsigned short u16;
typedef unsigned short u16x8 __attribute__((ext_vector_type(8)));
typedef _Float16 f16;
typedef _Float16 f16x8 __attribute__((ext_vector_type(8)));
typedef float f32x4 __attribute__((ext_vector_type(4)));

#define BATCH 32768
#define DIM   1024
#define NPAD  1024
#define DSTRIDE 2112

#define BARRIER()  asm volatile("s_barrier" ::: "memory")

// ---- f16 helpers ----
__device__ __forceinline__ u16 f2h(float f) {
    union { f16 h; u16 u; } v; v.h = (f16)f; return v.u;
}
__device__ __forceinline__ float h2f(u16 u) {
    union { u16 u; f16 h; } v; v.u = u; return (float)v.h;
}

#define MFMA16(a, b, c) __builtin_amdgcn_mfma_f32_16x16x32_f16(a, b, c, 0, 0, 0)

// ---------------------------------------------------------------------------
// prep: thresholds -> Bpk1 fragment-packed f16 (node row 1023 = 0; frozen)
// Bpk1[((n16*32 + kt)*64 + lane)*8 + j] = T[n16*16 + mr][kt*32 + kg*8 + j]
// ---------------------------------------------------------------------------
__global__ __launch_bounds__(256) void prep_tp(const float* __restrict__ t,
                                               u16* __restrict__ Bpk1) {
    int o = (blockIdx.x * 256 + threadIdx.x) * 4;
    int n16  = o >> 14;
    int kt   = (o >> 9) & 31;
    int lane = (o >> 3) & 63;
    int j0   = o & 7;
    int mr = lane & 15, kg = lane >> 4;
    int node = n16 * 16 + mr;
    int k0  = kt * 32 + kg * 8 + j0;
    ushort4 v = make_ushort4(0, 0, 0, 0);
    if (node < 1023) {
        const float* src = t + (size_t)node * 1024 + k0;
        v.x = f2h(src[0]); v.y = f2h(src[1]);
        v.z = f2h(src[2]); v.w = f2h(src[3]);
    }
    *(ushort4*)&Bpk1[o] = v;
}

// ---------------------------------------------------------------------------
// prep: L (1024x1024 f32, [leaf][out]) -> BpkL fragment-packed f16 (frozen)
// ---------------------------------------------------------------------------
__global__ __launch_bounds__(256) void prep_lt(const float* __restrict__ L,
                                               u16* __restrict__ BpkL) {
    int o = (blockIdx.x * 256 + threadIdx.x) * 4;
    int b16  = o >> 14;
    int kt   = (o >> 9) & 31;
    int lane = (o >> 3) & 63;
    int j0   = o & 7;
    int mr = lane & 15, kg = lane >> 4;
    int col = b16 * 16 + mr;
    int k0  = kt * 32 + kg * 8 + j0;
    ushort4 v;
    v.x = f2h(L[(size_t)(k0 + 0) * 1024 + col]);
    v.y = f2h(L[(size_t)(k0 + 1) * 1024 + col]);
    v.z = f2h(L[(size_t)(k0 + 2) * 1024 + col]);
    v.w = f2h(L[(size_t)(k0 + 3) * 1024 + col]);
    *(ushort4*)&BpkL[o] = v;
}

// ---------------------------------------------------------------------------
// MEGA KERNEL
// ---------------------------------------------------------------------------
__global__ __launch_bounds__(1024, 1) void megak(
    const float* __restrict__ X, const u16* __restrict__ Bpk1,
    const u16* __restrict__ BpkL, float* __restrict__ out)
{
    __shared__ __align__(16) char lds[135168];
    const int t = threadIdx.x, wid = t >> 6, lane = t & 63;
    const int mr = lane & 15, kg = lane >> 4;
    const int rb = blockIdx.x * 64;
    const int fq = kg * 4;

    const u16* bbase1[4];
#pragma unroll
    for (int n = 0; n < 4; ++n)
        bbase1[n] = Bpk1 + (size_t)(wid * 4 + n) * 16384 + (unsigned)lane * 8u;

    f16x8 bA[4], bB[4];

    // ---------------- phase A: X f32 -> f16 LDS [64][2048B] ----------------
    // row byte w holds global f16-k-byte (w ^ ((row&7)<<4));
    // chunk c (8 rows, 16KB): dest = lds + c*16384 + t*16.
    {
        const unsigned woff = (unsigned)((wid & 1) * 1024 + lane * 16);
        const int rowbase = wid >> 1;
        float4 xlo[8], xhi[8];
#pragma unroll
        for (int c = 0; c < 8; ++c) {
            int row = c * 8 + rowbase;
            unsigned key = (unsigned)(row & 7) << 4;
            const float* src = X + (size_t)(rb + row) * 1024 + ((woff ^ key) >> 1);
            xlo[c] = *(const float4*)src;
            xhi[c] = *(const float4*)(src + 4);
        }
        // b1(0) issued AFTER X loads (youngest) -> stays in flight
#pragma unroll
        for (int n = 0; n < 4; ++n) bA[n] = *(const f16x8*)(bbase1[n]);
#pragma unroll
        for (int c = 0; c < 8; ++c) {
            u16x8 h;
            h[0] = f2h(xlo[c].x); h[1] = f2h(xlo[c].y);
            h[2] = f2h(xlo[c].z); h[3] = f2h(xlo[c].w);
            h[4] = f2h(xhi[c].x); h[5] = f2h(xhi[c].y);
            h[6] = f2h(xhi[c].z); h[7] = f2h(xhi[c].w);
            *(u16x8*)(lds + c * 16384 + t * 16) = h;
        }
    }
    asm volatile("s_waitcnt lgkmcnt(0)" ::: "memory");
    BARRIER();

    // ---------------- phase B: gemm1 barrier-free K-loop ----------------
    const unsigned keyA1 = (unsigned)(mr & 7) << 4;
    unsigned offA1[4];
#pragma unroll
    for (int m = 0; m < 4; ++m) offA1[m] = (unsigned)((m * 16 + mr) * 2048);

    f32x4 acc[4][4];
#pragma unroll
    for (int m = 0; m < 4; ++m)
#pragma unroll
        for (int n = 0; n < 4; ++n) acc[m][n] = (f32x4){0.f, 0.f, 0.f, 0.f};

    auto step1 = [&](int kt, f16x8 (&bu)[4], f16x8 (&bl)[4]) {
        if (kt + 1 < 32) {
#pragma unroll
            for (int n = 0; n < 4; ++n)
                bl[n] = *(const f16x8*)(bbase1[n] + (unsigned)(kt + 1) * 512u);
        }
        const unsigned ko = ((unsigned)(kt * 64) + (unsigned)kg * 16u) ^ keyA1;
        f16x8 a[4];
#pragma unroll
        for (int m = 0; m < 4; ++m)
            a[m] = *(const f16x8*)(lds + offA1[m] + ko);
        __builtin_amdgcn_s_setprio(1);
#pragma unroll
        for (int m = 0; m < 4; ++m)
#pragma unroll
            for (int n = 0; n < 4; ++n)
                acc[m][n] = MFMA16(a[m], bu[n], acc[m][n]);
        __builtin_amdgcn_s_setprio(0);
    };

#pragma unroll 1
    for (int k2 = 0; k2 < 16; ++k2) {
        step1(2 * k2, bA, bB);
        step1(2 * k2 + 1, bB, bA);
    }

    // ---------------- phase C: sigmoid -> d into LDS [64][2112B] ----------
    // byte = row*2112 + ((2 + col*2) ^ ((row>>2)&3)<<4)
    __syncthreads();     // all waves done reading Xh-LDS
#pragma unroll
    for (int m = 0; m < 4; ++m)
#pragma unroll
        for (int j = 0; j < 4; ++j) {
            int row = m * 16 + fq + j;
            unsigned wkey = ((unsigned)((row >> 2) & 3)) << 4;
            char* drow = lds + row * DSTRIDE;
#pragma unroll
            for (int n = 0; n < 4; ++n) {
                int col = wid * 64 + n * 16 + mr;
                float s = acc[m][n][j];
                float dv = 1.0f / (1.0f + __expf(-s));
                *(u16*)(drow + ((2u + 2u * (unsigned)col) ^ wkey)) = f2h(dv);
            }
        }
    __syncthreads();     // d complete

    // ---------------- phase D: tree expansion (d from LDS, vector reads) ---
    u16x8 pk[4][2];
#pragma unroll
    for (int r = 0; r < 4; ++r) {
        const int lrow = wid * 4 + r;
        const char* dro = lds + lrow * DSTRIDE;
        const unsigned dkey = ((unsigned)((lrow >> 2) & 3)) << 4;
        const int l = lane;

        float prod = 1.0f;
#pragma unroll
        for (int lev = 0; lev < 6; lev++) {
            int node = (1 << lev) - 1 + (l >> (6 - lev));
            int bit  = (l >> (5 - lev)) & 1;
            float v = h2f(*(const u16*)(dro + ((2u + 2u * (unsigned)node) ^ dkey)));
            prod *= bit ? (1.0f - v) : v;
        }
        float d6 = h2f(*(const u16*)(dro + ((2u + 2u * (unsigned)(63 + l)) ^ dkey)));
        ushort2 p7 = *(const ushort2*)(dro + ((256u + 4u * (unsigned)l) ^ dkey));
        ushort4 p8 = *(const ushort4*)(dro + ((512u + 8u * (unsigned)l) ^ dkey));
        u16x8   p9 = *(const u16x8*)(dro + ((1024u + 16u * (unsigned)l) ^ dkey));
        float d7[2] = {h2f(p7.x), h2f(p7.y)};
        float d8[4] = {h2f(p8.x), h2f(p8.y), h2f(p8.z), h2f(p8.w)};
        float d9[8];
#pragma unroll
        for (int j = 0; j < 8; j++) d9[j] = h2f(p9[j]);

        u16 outv[16];
#pragma unroll
        for (int j = 0; j < 16; j++) {
            float f6 = (j >> 3) ? (1.0f - d6) : d6;
            float v7 = d7[j >> 3];  float f7 = ((j >> 2) & 1) ? (1.0f - v7) : v7;
            float v8 = d8[j >> 2];  float f8 = ((j >> 1) & 1) ? (1.0f - v8) : v8;
            float v9 = d9[j >> 1];  float f9 = (j & 1) ? (1.0f - v9) : v9;
            outv[j] = f2h(prod * f6 * f7 * f8 * f9);
        }
        pk[r][0] = (u16x8){outv[0], outv[1], outv[2], outv[3],
                           outv[4], outv[5], outv[6], outv[7]};
        pk[r][1] = (u16x8){outv[8], outv[9], outv[10], outv[11],
                           outv[12], outv[13], outv[14], outv[15]};
    }
    __syncthreads();     // all d reads done before probs overwrite

    // packed probs write, slot-XOR (kt&7)
    {
        const int ktw = lane >> 1, kg0 = (lane & 1) * 2;
        const unsigned K = (unsigned)(ktw & 7);
#pragma unroll
        for (int r = 0; r < 4; ++r) {
            const int lrow = wid * 4 + r;
            const int m = lrow >> 4, mrr = lrow & 15;
            char* base = lds + (((ktw << 2) + m) << 10);
            unsigned s0 = ((unsigned)(kg0 * 16 + mrr)) ^ K;
            unsigned s1 = ((unsigned)((kg0 + 1) * 16 + mrr)) ^ K;
            *(u16x8*)(base + s0 * 16) = pk[r][0];
            *(u16x8*)(base + s1 * 16) = pk[r][1];
        }
    }
    __syncthreads();     // probs complete

    // ---------------- phase E: gemm2 barrier-free K-loop ----------------
    const u16* bbase2 = BpkL + (size_t)(wid * 4) * 16384 + (unsigned)lane * 8u;

#pragma unroll
    for (int m = 0; m < 4; ++m)
#pragma unroll
        for (int n = 0; n < 4; ++n) acc[m][n] = (f32x4){0.f, 0.f, 0.f, 0.f};

#pragma unroll
    for (int n = 0; n < 4; ++n) bA[n] = *(const f16x8*)(bbase2 + n * 16384);

    auto step2 = [&](int kt, f16x8 (&bu)[4], f16x8 (&bl)[4]) {
        if (kt + 1 < 32) {
#pragma unroll
            for (int n = 0; n < 4; ++n)
                bl[n] = *(const f16x8*)(bbase2 + n * 16384 + (unsigned)(kt + 1) * 512u);
        }
        const unsigned sl = ((unsigned)(lane ^ (kt & 7))) << 4;
        f16x8 a[4];
#pragma unroll
        for (int m = 0; m < 4; ++m)
            a[m] = *(const f16x8*)(lds + (((kt << 2) + m) << 10) + sl);
        __builtin_amdgcn_s_setprio(1);
#pragma unroll
        for (int m = 0; m < 4; ++m)
#pragma unroll
            for (int n = 0; n < 4; ++n)
                acc[m][n] = MFMA16(a[m], bu[n], acc[m][n]);
        __builtin_amdgcn_s_setprio(0);
    };

#pragma unroll 1
    for (int k2 = 0; k2 < 16; ++k2) {
        step2(2 * k2, bA, bB);
        step2(2 * k2 + 1, bB, bA);
    }

    __syncthreads();     // all probs reads done before red reuse

    // ---------------- phase F: in-register softmax ----------------
    float* red  = (float*)lds;            // [64][16] max
    float* red2 = (float*)(lds + 4096);   // [64][16] sum

    float mx[4][4];
#pragma unroll
    for (int m = 0; m < 4; ++m)
#pragma unroll
        for (int j = 0; j < 4; ++j) {
            float v = acc[m][0][j];
#pragma unroll
            for (int n = 1; n < 4; ++n) v = fmaxf(v, acc[m][n][j]);
#pragma unroll
            for (int off = 1; off < 16; off <<= 1)
                v = fmaxf(v, __shfl_xor(v, off));
            mx[m][j] = v;
        }
    if (mr == 0) {
#pragma unroll
        for (int m = 0; m < 4; ++m)
#pragma unroll
            for (int j = 0; j < 4; ++j)
                red[(m * 16 + fq + j) * 16 + wid] = mx[m][j];
    }
    __syncthreads();
    if (t < 64) {
        float v = red[t * 16];
#pragma unroll
        for (int w = 1; w < 16; ++w) v = fmaxf(v, red[t * 16 + w]);
        red[t * 16] = v;
    }
    __syncthreads();

    float sm[4][4];
#pragma unroll
    for (int m = 0; m < 4; ++m)
#pragma unroll
        for (int j = 0; j < 4; ++j) {
            float M = red[(m * 16 + fq + j) * 16];
            float s = 0.f;
#pragma unroll
            for (int n = 0; n < 4; ++n) {
                float e = __expf(acc[m][n][j] - M);
                acc[m][n][j] = e;
                s += e;
            }
#pragma unroll
            for (int off = 1; off < 16; off <<= 1)
                s += __shfl_xor(s, off);
            sm[m][j] = s;
        }
    if (mr == 0) {
#pragma unroll
        for (int m = 0; m < 4; ++m)
#pragma unroll
            for (int j = 0; j < 4; ++j)
                red2[(m * 16 + fq + j) * 16 + wid] = sm[m][j];
    }
    __syncthreads();
    if (t < 64) {
        float v = 0.f;
#pragma unroll
        for (int w = 0; w < 16; ++w) v += red2[t * 16 + w];
        red2[t * 16] = 1.0f / v;
    }
    __syncthreads();

#pragma unroll
    for (int m = 0; m < 4; ++m)
#pragma unroll
        for (int j = 0; j < 4; ++j) {
            int grow = rb + m * 16 + fq + j;
            float inv = red2[(m * 16 + fq + j) * 16];
#pragma unroll
            for (int n = 0; n < 4; ++n) {
                int gcol = wid * 64 + n * 16 + mr;
                out[(size_t)grow * 1024 + gcol] = acc[m][n][j] * inv;
            }
        }
}

// ---------------------------------------------------------------------------
extern "C" void kernel_launch(void* const* d_in, const int* in_sizes, int n_in,
                              void* d_out, int out_size, void* d_ws, size_t ws_size,
                              hipStream_t stream) {
    const float* x  = (const float*)d_in[0];
    const float* ft = (const float*)d_in[1];
    const float* lp = (const float*)d_in[2];
    float* out = (float*)d_out;
    char* ws = (char*)d_ws;

    // ws layout: Bpk1 2Mi | BpkL 2Mi
    u16* Bpk1 = (u16*)ws;
    u16* BpkL = Bpk1 + (size_t)NPAD * DIM;

    prep_tp<<<1024, 256, 0, stream>>>(ft, Bpk1);
    prep_lt<<<1024, 256, 0, stream>>>(lp, BpkL);
    megak<<<512, 1024, 0, stream>>>(x, Bpk1, BpkL, out);
}